// Round 7
// baseline (388.943 us; speedup 1.0000x reference)
//
#include <hip/hip_runtime.h>
#include <hip/hip_bf16.h>

// out = tril((2Q - tril(QK^T)K) K^T) V per (b,h): two fused causal passes of
// Y = tril(X K^T) W  (pass0: X=Q,W=K -> o2; pass1: X=2Q-o2, W=V).
// R7 = R4 (known-good paired-strip WG, 2-barrier iter, grid 512) with BN=128:
// two 64-row s-blocks staged per barrier pair -> half the barrier events.
// P-scratch reused strip-B-then-strip-A (same-wave DS ordering, as R4's o2
// roundtrip). Kernel renamed to defeat any stale-artifact reuse.

typedef __bf16 bf16x8 __attribute__((ext_vector_type(8)));
typedef __bf16 bf16x4 __attribute__((ext_vector_type(4)));
typedef __bf16 bf16x2 __attribute__((ext_vector_type(2)));
typedef float  f32x4  __attribute__((ext_vector_type(4)));

#define MFMA16(a, b, c) __builtin_amdgcn_mfma_f32_16x16x32_bf16((a), (b), (c), 0, 0, 0)

static constexpr int S  = 2048;
static constexpr int H  = 16;
static constexpr int D  = 64;
static constexpr int RS = 3 * H * D;   // 3072 floats between consecutive s rows
static constexpr int BN = 128;         // key rows per iteration (2 x 64 sub-blocks)
static constexpr int LR = 72;          // row stride (u16) for 64-col tiles
static constexpr int LW = 136;         // row stride (u16) for 128-col tiles

__global__ __launch_bounds__(256, 2)
void ttt_kernel_r7(const float* __restrict__ qkv, float* __restrict__ out)
{
    __shared__ __bf16 ldsS[128 * LR];  // Q staging (stride LR) -> per-wave P/o2 scratch (stride LW)
    __shared__ __bf16 ldsK[BN * LR];   // K tile row-major [s][d], 128 rows
    __shared__ __bf16 ldsW[D  * LW];   // W^T [d][ (s&64) + ((s&63) ^ (d&56)) ]

    const int tid  = threadIdx.x;
    const int wv   = tid >> 6;
    const int lane = tid & 63;
    const int q    = lane >> 4;        // quad 0..3
    const int l16  = lane & 15;

    // i bits: [2:0]=bh_low (XCD pin), [6:3]=p, [8:7]=bh_high
    const int i  = (int)blockIdx.x;
    const int p  = (i >> 3) & 15;
    const int bh = (i & 7) + 8 * (i >> 7);
    const int b  = bh >> 4;
    const int h  = bh & 15;
    const int tA = 64 * p;             // light strip
    const int tB = 64 * (31 - p);      // heavy strip
    const int nA2 = (p >> 1) + 1;      // 128-wide s-blocks for strip A
    const int nB2 = (33 - p) >> 1;     // 128-wide s-blocks for strip B (>= nA2)

    const float* baseQ = qkv + (size_t)b * S * RS + h * D;
    const float* baseK = baseQ + H * D;
    const float* baseV = baseQ + 2 * H * D;

    // staging coords: thread owns rows r2,r2+1 cols cb..cb+7 of a 64x64 sub-tile
    const int r2 = (tid >> 3) * 2;
    const int cb = (tid & 7) * 8;

    // ---- stage Q for both strips (128 rows) -> ldsS row-major [t][d], stride LR ----
    {
        const int r   = tid >> 1;
        const int gr  = (r < 64) ? (tA + r) : (tB + r - 64);
        const int cbq = (tid & 1) * 32;
        const float* pq = baseQ + (size_t)gr * RS + cbq;
        __bf16* dst = ldsS + r * LR + cbq;
#pragma unroll
        for (int u = 0; u < 4; ++u) {
            f32x4 f0 = *(const f32x4*)(pq + u * 8);
            f32x4 f1 = *(const f32x4*)(pq + u * 8 + 4);
            bf16x8 w;
#pragma unroll
            for (int j = 0; j < 4; ++j) { w[j] = (__bf16)f0[j]; w[4 + j] = (__bf16)f1[j]; }
            *(bf16x8*)(dst + u * 8) = w;
        }
    }

    f32x4 pk[8], pv[8];   // prefetch regs: [4*sub + 0..1]=row r2, [4*sub + 2..3]=row r2+1
    auto loadT = [&](f32x4* dst, const float* base, int s0) {   // one 64-row sub-block
        const float* pg = base + (size_t)(s0 + r2) * RS + cb;
        dst[0] = *(const f32x4*)(pg);
        dst[1] = *(const f32x4*)(pg + 4);
        dst[2] = *(const f32x4*)(pg + RS);
        dst[3] = *(const f32x4*)(pg + RS + 4);
    };
    loadT(pk, baseK, 0);
    loadT(pk + 4, baseK, 64);

    __syncthreads();   // Q staged

    // ---- hoist X B-frags: lane holds X[t = base+l16][d = kt*32+q*8+j] ----
    bf16x8 Xf[2][2];   // [strip][kt]
    const int rowA = wv * 16;
    const int rowB = 64 + wv * 16;
#pragma unroll
    for (int kt = 0; kt < 2; ++kt) {
        Xf[0][kt] = *(bf16x8*)(ldsS + (rowA + l16) * LR + kt * 32 + q * 8);
        Xf[1][kt] = *(bf16x8*)(ldsS + (rowB + l16) * LR + kt * 32 + q * 8);
    }
    __bf16* sc = ldsS + (wv * 16) * LW;   // wave-private scratch, 16 rows x LW
    const int rot = 8 * l16;              // P-region rotation swizzle (mod 128)

    const f32x4 zero4 = {0.f, 0.f, 0.f, 0.f};
    f32x4 Y[2][4];                     // [strip][nd]
#pragma unroll
    for (int st = 0; st < 2; ++st)
#pragma unroll
        for (int nd = 0; nd < 4; ++nd) Y[st][nd] = zero4;

    for (int pass = 0; pass < 2; ++pass) {
        for (int jb = 0; jb < nB2; ++jb) {
            __syncthreads();                       // prior iter's tile reads done
            // ---- commit prefetched 128-row tile to LDS (two 64-row sub-blocks) ----
#pragma unroll
            for (int sub = 0; sub < 2; ++sub) {
                const f32x4* kk = pk + 4 * sub;
                bf16x8 w0, w1;
#pragma unroll
                for (int jj = 0; jj < 4; ++jj) {
                    w0[jj] = (__bf16)kk[0][jj]; w0[4 + jj] = (__bf16)kk[1][jj];
                    w1[jj] = (__bf16)kk[2][jj]; w1[4 + jj] = (__bf16)kk[3][jj];
                }
                *(bf16x8*)(ldsK + (64 * sub + r2) * LR + cb)     = w0;
                *(bf16x8*)(ldsK + (64 * sub + r2 + 1) * LR + cb) = w1;
                const f32x4* ss = ((pass == 0) ? pk : pv) + 4 * sub;
#pragma unroll
                for (int jj = 0; jj < 8; ++jj) {
                    const int d = cb + jj;
                    bf16x2 w;
                    w[0] = (__bf16)((jj < 4) ? ss[0][jj & 3] : ss[1][jj & 3]);
                    w[1] = (__bf16)((jj < 4) ? ss[2][jj & 3] : ss[3][jj & 3]);
                    *(bf16x2*)(ldsW + d * LW + 64 * sub + (r2 ^ (d & 56))) = w;
                }
            }
            __syncthreads();                       // tile visible

            // ---- prefetch next tile (drains a full GEMM-phase later) ----
            if (jb + 1 < nB2) {
                loadT(pk, baseK, 128 * (jb + 1));
                loadT(pk + 4, baseK, 128 * (jb + 1) + 64);
                if (pass == 1) {
                    loadT(pv, baseV, 128 * (jb + 1));
                    loadT(pv + 4, baseV, 128 * (jb + 1) + 64);
                }
            } else if (pass == 0) {
                loadT(pk, baseK, 0);  loadT(pk + 4, baseK, 64);
                loadT(pv, baseV, 0);  loadT(pv + 4, baseV, 64);
            }

            const bool actA = (jb < nA2);          // block-uniform branch

            // ---- GEMM1-T both strips (shared kf): Pt[s][t] = sum_d K[s][d] X[t][d] ----
            f32x4 PtA[8], PtB[8];
#pragma unroll
            for (int mi = 0; mi < 8; ++mi) { PtA[mi] = zero4; PtB[mi] = zero4; }
#pragma unroll
            for (int kt = 0; kt < 2; ++kt) {
#pragma unroll
                for (int mi = 0; mi < 8; ++mi) {
                    bf16x8 kf = *(bf16x8*)(ldsK + (mi * 16 + l16) * LR + kt * 32 + q * 8);
                    PtB[mi] = MFMA16(kf, Xf[1][kt], PtB[mi]);
                    if (actA) PtA[mi] = MFMA16(kf, Xf[0][kt], PtA[mi]);
                }
            }

            // ---- strip B: mask + pack + b64 store, then GEMM2 ----
            {
                const int tgB = tB + wv * 16 + l16;
#pragma unroll
                for (int mi = 0; mi < 8; ++mi) {
                    const int sg0 = jb * BN + mi * 16 + q * 4;
                    bf16x4 pw;
#pragma unroll
                    for (int r = 0; r < 4; ++r)
                        pw[r] = (__bf16)((sg0 + r <= tgB) ? PtB[mi][r] : 0.0f);
                    *(bf16x4*)(sc + l16 * LW + ((mi * 16 + q * 4 + rot) & 127)) = pw;
                }
#pragma unroll
                for (int kt = 0; kt < 4; ++kt) {
                    bf16x8 af = *(bf16x8*)(sc + l16 * LW + ((kt * 32 + q * 8 + rot) & 127));
#pragma unroll
                    for (int nd = 0; nd < 4; ++nd) {
                        const int d = l16 + nd * 16;
                        const int o = kt * 32 + q * 8;
                        bf16x8 wf = *(bf16x8*)(ldsW + d * LW + (o & 64) + ((o & 63) ^ (d & 56)));
                        Y[1][nd] = MFMA16(af, wf, Y[1][nd]);
                    }
                }
            }

            // ---- strip A: same, reusing the wave-private scratch ----
            if (actA) {
                const int tgA = tA + wv * 16 + l16;
#pragma unroll
                for (int mi = 0; mi < 8; ++mi) {
                    const int sg0 = jb * BN + mi * 16 + q * 4;
                    bf16x4 pw;
#pragma unroll
                    for (int r = 0; r < 4; ++r)
                        pw[r] = (__bf16)((sg0 + r <= tgA) ? PtA[mi][r] : 0.0f);
                    *(bf16x4*)(sc + l16 * LW + ((mi * 16 + q * 4 + rot) & 127)) = pw;
                }
#pragma unroll
                for (int kt = 0; kt < 4; ++kt) {
                    bf16x8 af = *(bf16x8*)(sc + l16 * LW + ((kt * 32 + q * 8 + rot) & 127));
#pragma unroll
                    for (int nd = 0; nd < 4; ++nd) {
                        const int d = l16 + nd * 16;
                        const int o = kt * 32 + q * 8;
                        bf16x8 wf = *(bf16x8*)(ldsW + d * LW + (o & 64) + ((o & 63) ^ (d & 56)));
                        Y[0][nd] = MFMA16(af, wf, Y[0][nd]);
                    }
                }
            }
        }

        if (pass == 0) {
            // per strip: o2 (C-layout) -> wave-private scratch plain [t][d],
            // reread as B-frags, Xf = 2Q - o2; reset Y. Sequential strips reuse sc.
#pragma unroll
            for (int st = 0; st < 2; ++st) {
#pragma unroll
                for (int nd = 0; nd < 4; ++nd)
#pragma unroll
                    for (int r = 0; r < 4; ++r)
                        sc[(q * 4 + r) * LW + l16 + nd * 16] = (__bf16)Y[st][nd][r];
#pragma unroll
                for (int kt = 0; kt < 2; ++kt) {
                    bf16x8 of = *(bf16x8*)(sc + l16 * LW + kt * 32 + q * 8);
#pragma unroll
                    for (int jj = 0; jj < 8; ++jj)
                        Xf[st][kt][jj] = (__bf16)(2.0f * (float)Xf[st][kt][jj] - (float)of[jj]);
                }
#pragma unroll
                for (int nd = 0; nd < 4; ++nd) Y[st][nd] = zero4;
            }
        } else {
            // out[b][t][h][d] fp32, both strips
#pragma unroll
            for (int st = 0; st < 2; ++st) {
                const int tb = (st == 0) ? tA : tB;
#pragma unroll
                for (int nd = 0; nd < 4; ++nd)
#pragma unroll
                    for (int r = 0; r < 4; ++r) {
                        const int t = tb + wv * 16 + q * 4 + r;
                        const int d = l16 + nd * 16;
                        out[(((size_t)b * S + t) * H + h) * D + d] = Y[st][nd][r];
                    }
            }
        }
    }
}

extern "C" void kernel_launch(void* const* d_in, const int* in_sizes, int n_in,
                              void* d_out, int out_size, void* d_ws, size_t ws_size,
                              hipStream_t stream)
{
    const float* qkv = (const float*)d_in[0];
    float* out = (float*)d_out;
    ttt_kernel_r7<<<dim3(512), 256, 0, stream>>>(qkv, out);   // 16 pairs x 32 bh
}